// Round 1
// baseline (1353.463 us; speedup 1.0000x reference)
//
#include <hip/hip_runtime.h>

// LinearAttention: B=16, T=4096, D=512, LR=0.01
//   q,k,v = x @ W^T ; S += LR * sum_b v k^T (before readout) ; out = S q
// Chunked: chunk = 64 time steps = 1024 rows (time-major r = t*16 + b).
// Causality is at time-step granularity = 16 rows = one MFMA tile.
//
// MFMA convention (gfx950 16x16x32 bf16):
//   D[m][n] = sum_k A[m][k] B[k][n]
//   A-frag: lane holds A[m=lane&15][k=(lane>>4)*8 + j]  (8 consecutive k)
//   B-frag: lane holds B[k=(lane>>4)*8+j][n=lane&15]    (8 consecutive k, fixed n)
//   C/D   : D[row=(lane>>4)*4+i][col=lane&15]
// => both operands want reduction-dim-contiguous storage. We store:
//   qb,kb: [r][e] (e contig)   kt: [c][e][rl] (rl contig)   vt: [c][d][rl]

#define LR_ 0.01f

typedef __attribute__((ext_vector_type(8))) short   short8v;   // bf16x8 frag
typedef __attribute__((ext_vector_type(4))) float   f32x4;     // acc
typedef __attribute__((ext_vector_type(4))) unsigned short us4;
typedef __attribute__((ext_vector_type(8))) unsigned short us8;

__device__ __forceinline__ unsigned short f2bf(float f) {
    unsigned int u = __float_as_uint(f);
    return (unsigned short)((u + 0x7FFFu + ((u >> 16) & 1u)) >> 16); // RNE
}

// ---------------------------------------------------------------- K0: fp32->bf16
__global__ __launch_bounds__(256) void cvt_kernel(const float* __restrict__ s,
                                                  unsigned short* __restrict__ d, int n) {
    int i = (blockIdx.x * 256 + threadIdx.x) * 8;
    if (i + 8 <= n) {
        f32x4 a = *(const f32x4*)(s + i);
        f32x4 b = *(const f32x4*)(s + i + 4);
        us8 o;
        #pragma unroll
        for (int j = 0; j < 4; j++) { o[j] = f2bf(a[j]); o[j + 4] = f2bf(b[j]); }
        *(us8*)(d + i) = o;
    } else {
        for (; i < n; i++) d[i] = f2bf(s[i]);
    }
}

// ---------------------------------------------------------------- K1: projections
// C[r][n] = sum_d xb[i(r)][d] * W[n][d], 128x128 tile, direct global frag loads.
// mat 0 -> qb[r][e]; mat 1 -> kb[r][e] + kt[c][e][rl]; mat 2 -> vt[c][d][rl]
__global__ __launch_bounds__(256) void proj_kernel(
    const unsigned short* __restrict__ xb, const unsigned short* __restrict__ wb,
    unsigned short* __restrict__ qb, unsigned short* __restrict__ kb,
    unsigned short* __restrict__ kt, unsigned short* __restrict__ vt) {
    const int colTile = blockIdx.x;            // 0..3
    const int rowTile = blockIdx.y;            // 0..511
    const int mat     = blockIdx.z;            // 0..2
    const int tid = threadIdx.x, wid = tid >> 6, lane = tid & 63;
    const int quad = lane >> 4, l16 = lane & 15;
    const int r0 = rowTile * 128 + (wid >> 1) * 64;  // wave row base (r-space)
    const int n0 = colTile * 128 + (wid & 1) * 64;   // wave col base (e-space)
    const unsigned short* wmat = wb + mat * (512 * 512);

    f32x4 acc[4][4];
    #pragma unroll
    for (int a = 0; a < 4; a++)
        #pragma unroll
        for (int b = 0; b < 4; b++) acc[a][b] = (f32x4)0.f;

    const unsigned short* arow[4];
    const unsigned short* brow[4];
    #pragma unroll
    for (int mt = 0; mt < 4; mt++) {
        int r = r0 + mt * 16 + l16;
        int i = ((r & 15) << 12) | (r >> 4);   // x row = b*4096 + t
        arow[mt] = xb + i * 512 + quad * 8;
    }
    #pragma unroll
    for (int nt = 0; nt < 4; nt++) {
        int n = n0 + nt * 16 + l16;
        brow[nt] = wmat + n * 512 + quad * 8;
    }

    for (int kk = 0; kk < 512; kk += 32) {
        short8v a[4], b[4];
        #pragma unroll
        for (int mt = 0; mt < 4; mt++) a[mt] = *(const short8v*)(arow[mt] + kk);
        #pragma unroll
        for (int nt = 0; nt < 4; nt++) b[nt] = *(const short8v*)(brow[nt] + kk);
        #pragma unroll
        for (int mt = 0; mt < 4; mt++)
            #pragma unroll
            for (int nt = 0; nt < 4; nt++)
                acc[mt][nt] = __builtin_amdgcn_mfma_f32_16x16x32_bf16(
                    a[mt], b[nt], acc[mt][nt], 0, 0, 0);
    }

    #pragma unroll
    for (int mt = 0; mt < 4; mt++) {
        int rbase = r0 + mt * 16 + quad * 4;             // 4 consecutive rows
        int c = rbase >> 10, rl = rbase & 1023;
        #pragma unroll
        for (int nt = 0; nt < 4; nt++) {
            int e = n0 + nt * 16 + l16;
            unsigned short h[4];
            #pragma unroll
            for (int i = 0; i < 4; i++) h[i] = f2bf(acc[mt][nt][i]);
            if (mat == 0) {
                #pragma unroll
                for (int i = 0; i < 4; i++) qb[(rbase + i) * 512 + e] = h[i];
            } else if (mat == 1) {
                #pragma unroll
                for (int i = 0; i < 4; i++) kb[(rbase + i) * 512 + e] = h[i];
                us4 p; p[0] = h[0]; p[1] = h[1]; p[2] = h[2]; p[3] = h[3];
                *(us4*)(kt + (c * 512 + e) * 1024 + rl) = p;
            } else {
                us4 p; p[0] = h[0]; p[1] = h[1]; p[2] = h[2]; p[3] = h[3];
                *(us4*)(vt + (c * 512 + e) * 1024 + rl) = p;
            }
        }
    }
}

// ---------------------------------------------------------------- K2: per-chunk G = sum_r v (x) k
// G[c][d][e] = sum_{rl<1024} vt[c][d][rl] * kt[c][e][rl]   (all-natural frags)
__global__ __launch_bounds__(256) void state_kernel(
    const unsigned short* __restrict__ kt, const unsigned short* __restrict__ vt,
    float* __restrict__ G) {
    const int c = blockIdx.y;
    const int dTile = blockIdx.x >> 2, eTile = blockIdx.x & 3;
    const int tid = threadIdx.x, wid = tid >> 6, lane = tid & 63;
    const int quad = lane >> 4, l16 = lane & 15;
    const int d0 = dTile * 128 + (wid >> 1) * 64;
    const int e0 = eTile * 128 + (wid & 1) * 64;

    f32x4 acc[4][4];
    #pragma unroll
    for (int a = 0; a < 4; a++)
        #pragma unroll
        for (int b = 0; b < 4; b++) acc[a][b] = (f32x4)0.f;

    const unsigned short* ar[4];
    const unsigned short* br[4];
    #pragma unroll
    for (int mt = 0; mt < 4; mt++) ar[mt] = vt + (c * 512 + d0 + mt * 16 + l16) * 1024 + quad * 8;
    #pragma unroll
    for (int nt = 0; nt < 4; nt++) br[nt] = kt + (c * 512 + e0 + nt * 16 + l16) * 1024 + quad * 8;

    for (int rl = 0; rl < 1024; rl += 32) {
        short8v a[4], b[4];
        #pragma unroll
        for (int mt = 0; mt < 4; mt++) a[mt] = *(const short8v*)(ar[mt] + rl);
        #pragma unroll
        for (int nt = 0; nt < 4; nt++) b[nt] = *(const short8v*)(br[nt] + rl);
        #pragma unroll
        for (int mt = 0; mt < 4; mt++)
            #pragma unroll
            for (int nt = 0; nt < 4; nt++)
                acc[mt][nt] = __builtin_amdgcn_mfma_f32_16x16x32_bf16(
                    a[mt], b[nt], acc[mt][nt], 0, 0, 0);
    }

    float* g = G + (size_t)c * 262144;
    #pragma unroll
    for (int mt = 0; mt < 4; mt++)
        #pragma unroll
        for (int nt = 0; nt < 4; nt++)
            #pragma unroll
            for (int i = 0; i < 4; i++)
                g[(d0 + mt * 16 + quad * 4 + i) * 512 + (e0 + nt * 16 + l16)] = acc[mt][nt][i];
}

// ---------------------------------------------------------------- K3: exclusive prefix over chunks
// Sp[c] = bf16( memory0 + LR * sum_{c'<c} G[c'] ), layout [c][d][e]
__global__ __launch_bounds__(256) void scan_kernel(const float* __restrict__ G,
                                                   const float* __restrict__ m0,
                                                   unsigned short* __restrict__ Sp) {
    int idx = blockIdx.x * 256 + threadIdx.x;   // (d,e) flat, 262144 total
    float s = m0[idx];
    for (int c = 0; c < 64; c++) {
        Sp[c * 262144 + idx] = f2bf(s);
        s += LR_ * G[c * 262144 + idx];
    }
}

// ---------------------------------------------------------------- K4: out = Q@Sp^T + intra
// One block = one chunk c x one 32-row tile (2 time steps). 4 waves x 128 cols.
__global__ __launch_bounds__(256) void out_kernel(
    const unsigned short* __restrict__ qb, const unsigned short* __restrict__ kb,
    const unsigned short* __restrict__ vt, const unsigned short* __restrict__ Sp,
    float* __restrict__ out) {
    __shared__ unsigned short Qs[32][520];   // +8 pad: 2-way-free banks for b128 reads
    __shared__ unsigned short Ss[32][40];    // scores tile (bf16, LR folded)

    // XCD swizzle: groups of 256 blocks = 8 chunks x 32 tiles; chunk = low 3 bits
    // so (assuming round-robin blockIdx->XCD) one chunk's L2 set stays on one XCD.
    const int bx = blockIdx.x;
    const int c  = (bx >> 8) * 8 + (bx & 7);     // 0..63
    const int it = (bx >> 3) & 31;               // row tile 0..31
    const int tid = threadIdx.x, wid = tid >> 6, lane = tid & 63;
    const int quad = lane >> 4, l16 = lane & 15;

    { // stage Q tile [32][512] to LDS (coalesced 16B)
        int row = tid >> 3, seg = tid & 7;
        const unsigned short* src = qb + (c * 1024 + it * 32 + row) * 512 + seg * 64;
        #pragma unroll
        for (int j = 0; j < 8; j++)
            *(short8v*)&Qs[row][seg * 64 + j * 8] = *(const short8v*)(src + j * 8);
    }
    __syncthreads();

    f32x4 acc[2][8];
    #pragma unroll
    for (int a = 0; a < 2; a++)
        #pragma unroll
        for (int b = 0; b < 8; b++) acc[a][b] = (f32x4)0.f;

    // ---- inter: acc += Q @ Sp[c]^T  (B-frag from Sp[c][d][e], e contig)
    {
        const unsigned short* spc = Sp + (size_t)c * 262144;
        const unsigned short* brow[8];
        #pragma unroll
        for (int nt = 0; nt < 8; nt++)
            brow[nt] = spc + (wid * 128 + nt * 16 + l16) * 512 + quad * 8;
        for (int kk = 0; kk < 512; kk += 32) {
            short8v a0 = *(const short8v*)&Qs[l16][kk + quad * 8];
            short8v a1 = *(const short8v*)&Qs[16 + l16][kk + quad * 8];
            #pragma unroll
            for (int nt = 0; nt < 8; nt++) {
                short8v b = *(const short8v*)(brow[nt] + kk);
                acc[0][nt] = __builtin_amdgcn_mfma_f32_16x16x32_bf16(a0, b, acc[0][nt], 0, 0, 0);
                acc[1][nt] = __builtin_amdgcn_mfma_f32_16x16x32_bf16(a1, b, acc[1][nt], 0, 0, 0);
            }
        }
    }

    // ---- intra: tile-causal (time granularity = 16 rows = 1 MFMA tile)
    const int mi = wid >> 1, ni = wid & 1;   // this wave's score sub-tile
    for (int j = 0; j <= it; j++) {
        f32x4 sc = (f32x4)0.f;
        const bool active = (j < it) | (ni <= mi);   // s_time <= t_time per tile
        if (active) {
            const unsigned short* krow =
                kb + (c * 1024 + j * 32 + ni * 16 + l16) * 512 + quad * 8;
            for (int kk = 0; kk < 512; kk += 32) {
                short8v a = *(const short8v*)&Qs[mi * 16 + l16][kk + quad * 8];
                short8v b = *(const short8v*)(krow + kk);
                sc = __builtin_amdgcn_mfma_f32_16x16x32_bf16(a, b, sc, 0, 0, 0);
            }
        }
        #pragma unroll
        for (int i = 0; i < 4; i++)
            Ss[mi * 16 + quad * 4 + i][ni * 16 + l16] = f2bf(sc[i] * LR_);
        __syncthreads();

        short8v as0 = *(const short8v*)&Ss[l16][quad * 8];
        short8v as1 = *(const short8v*)&Ss[16 + l16][quad * 8];
        #pragma unroll
        for (int nt = 0; nt < 8; nt++) {
            const short8v bv = *(const short8v*)(
                vt + (c * 512 + wid * 128 + nt * 16 + l16) * 1024 + j * 32 + quad * 8);
            acc[0][nt] = __builtin_amdgcn_mfma_f32_16x16x32_bf16(as0, bv, acc[0][nt], 0, 0, 0);
            acc[1][nt] = __builtin_amdgcn_mfma_f32_16x16x32_bf16(as1, bv, acc[1][nt], 0, 0, 0);
        }
        __syncthreads();
    }

    // ---- epilogue: out[b][t][d] fp32
    #pragma unroll
    for (int mt = 0; mt < 2; mt++)
        #pragma unroll
        for (int i = 0; i < 4; i++) {
            int r = c * 1024 + it * 32 + mt * 16 + quad * 4 + i;
            float* orow = out + (size_t)(r & 15) * (4096 * 512) + (size_t)(r >> 4) * 512;
            #pragma unroll
            for (int nt = 0; nt < 8; nt++)
                orow[wid * 128 + nt * 16 + l16] = acc[mt][nt][i];
        }
}

// ---------------------------------------------------------------- launch
extern "C" void kernel_launch(void* const* d_in, const int* in_sizes, int n_in,
                              void* d_out, int out_size, void* d_ws, size_t ws_size,
                              hipStream_t stream) {
    (void)in_sizes; (void)n_in; (void)out_size; (void)ws_size;
    const float* x  = (const float*)d_in[0];
    const float* Wq = (const float*)d_in[1];
    const float* Wk = (const float*)d_in[2];
    const float* Wv = (const float*)d_in[3];
    const float* m0 = (const float*)d_in[4];

    char* w = (char*)d_ws;
    // byte offsets (total ~418 MB of workspace)
    unsigned short* xb = (unsigned short*)(w + 0);            //  64 MB  x bf16
    unsigned short* wb = (unsigned short*)(w + 67108864);     // 1.5 MB  Wq|Wk|Wv bf16
    unsigned short* qb = (unsigned short*)(w + 68681728);     //  64 MB  [r][e]
    unsigned short* kb = (unsigned short*)(w + 135790592);    //  64 MB  [r][e]
    unsigned short* kt = (unsigned short*)(w + 202899456);    //  64 MB  [c][e][rl]
    unsigned short* vt = (unsigned short*)(w + 270008320);    //  64 MB  [c][d][rl]
    float*          G  = (float*)(w + 337117184);             //  64 MB  [c][d][e]
    unsigned short* Sp = (unsigned short*)(w + 404226048);    //  32 MB  [c][d][e]

    cvt_kernel<<<16384, 256, 0, stream>>>(x, xb, 33554432);
    cvt_kernel<<<128, 256, 0, stream>>>(Wq, wb, 262144);
    cvt_kernel<<<128, 256, 0, stream>>>(Wk, wb + 262144, 262144);
    cvt_kernel<<<128, 256, 0, stream>>>(Wv, wb + 524288, 262144);

    proj_kernel<<<dim3(4, 512, 3), 256, 0, stream>>>(xb, wb, qb, kb, kt, vt);
    state_kernel<<<dim3(16, 64), 256, 0, stream>>>(kt, vt, G);
    scan_kernel<<<1024, 256, 0, stream>>>(G, m0, Sp);
    out_kernel<<<2048, 256, 0, stream>>>(qb, kb, vt, Sp, (float*)d_out);
}

// Round 2
// 1286.623 us; speedup vs baseline: 1.0519x; 1.0519x over previous
//
#include <hip/hip_runtime.h>

// LinearAttention: B=16, T=4096, D=512, LR=0.01
//   q,k,v = x @ W^T ; S += LR * sum_b v k^T (before readout) ; out = S q
// Chunked: chunk = 64 time steps = 1024 rows (time-major r = t*16 + b).
// Causality is at time-step granularity = 16 rows = one MFMA tile.
//
// MFMA convention (gfx950 16x16x32 bf16):
//   D[m][n] = sum_k A[m][k] B[k][n]
//   A-frag: lane holds A[m=lane&15][k=(lane>>4)*8 + j]  (8 consecutive k)
//   B-frag: lane holds B[k=(lane>>4)*8+j][n=lane&15]    (8 consecutive k, fixed n)
//   C/D   : D[row=(lane>>4)*4+i][col=lane&15]
// Storage: qb,kb: [r][e] (e contig)   kt: [c][e][rl]   vt: [c][d][rl]
//
// R2 changes vs R1 (out_kernel was 6.5% MfmaUtil — serialization-bound):
//  * paired row-tiles (it, 31-it): every block = 33 j-tiles, no imbalance
//  * 4 j-tiles per round, one per wave: 4 indep score-acc chains per wave
//  * double-buffered score panel -> 1 barrier/round (was 2 per j-tile)
//  * proj/state: register double-buffer on the K-slab loads

#define LR_ 0.01f

typedef __attribute__((ext_vector_type(8))) short   short8v;   // bf16x8 frag
typedef __attribute__((ext_vector_type(4))) float   f32x4;     // acc
typedef __attribute__((ext_vector_type(4))) unsigned short us4;
typedef __attribute__((ext_vector_type(8))) unsigned short us8;

__device__ __forceinline__ unsigned short f2bf(float f) {
    unsigned int u = __float_as_uint(f);
    return (unsigned short)((u + 0x7FFFu + ((u >> 16) & 1u)) >> 16); // RNE
}

// ---------------------------------------------------------------- K0: fp32->bf16
__global__ __launch_bounds__(256) void cvt_kernel(const float* __restrict__ s,
                                                  unsigned short* __restrict__ d, int n) {
    int i = (blockIdx.x * 256 + threadIdx.x) * 8;
    if (i + 8 <= n) {
        f32x4 a = *(const f32x4*)(s + i);
        f32x4 b = *(const f32x4*)(s + i + 4);
        us8 o;
        #pragma unroll
        for (int j = 0; j < 4; j++) { o[j] = f2bf(a[j]); o[j + 4] = f2bf(b[j]); }
        *(us8*)(d + i) = o;
    } else {
        for (; i < n; i++) d[i] = f2bf(s[i]);
    }
}

// ---------------------------------------------------------------- K1: projections
// C[r][n] = sum_d xb[i(r)][d] * W[n][d], 128x128 tile, direct global frag loads
// with register double-buffering on the K slabs.
__global__ __launch_bounds__(256) void proj_kernel(
    const unsigned short* __restrict__ xb, const unsigned short* __restrict__ wb,
    unsigned short* __restrict__ qb, unsigned short* __restrict__ kb,
    unsigned short* __restrict__ kt, unsigned short* __restrict__ vt) {
    const int colTile = blockIdx.x;            // 0..3
    const int rowTile = blockIdx.y;            // 0..511
    const int mat     = blockIdx.z;            // 0..2
    const int tid = threadIdx.x, wid = tid >> 6, lane = tid & 63;
    const int quad = lane >> 4, l16 = lane & 15;
    const int r0 = rowTile * 128 + (wid >> 1) * 64;
    const int n0 = colTile * 128 + (wid & 1) * 64;
    const unsigned short* wmat = wb + mat * (512 * 512);

    f32x4 acc[4][4];
    #pragma unroll
    for (int a = 0; a < 4; a++)
        #pragma unroll
        for (int b = 0; b < 4; b++) acc[a][b] = (f32x4)0.f;

    const unsigned short* arow[4];
    const unsigned short* brow[4];
    #pragma unroll
    for (int mt = 0; mt < 4; mt++) {
        int r = r0 + mt * 16 + l16;
        int i = ((r & 15) << 12) | (r >> 4);   // x row = b*4096 + t
        arow[mt] = xb + i * 512 + quad * 8;
    }
    #pragma unroll
    for (int nt = 0; nt < 4; nt++) {
        int n = n0 + nt * 16 + l16;
        brow[nt] = wmat + n * 512 + quad * 8;
    }

    short8v a[2][4], b[2][4];
    #pragma unroll
    for (int mt = 0; mt < 4; mt++) a[0][mt] = *(const short8v*)(arow[mt]);
    #pragma unroll
    for (int nt = 0; nt < 4; nt++) b[0][nt] = *(const short8v*)(brow[nt]);

    #pragma unroll 2
    for (int kk = 0; kk < 512; kk += 32) {
        const int cur = (kk >> 5) & 1, nxt = cur ^ 1;
        if (kk < 480) {
            #pragma unroll
            for (int mt = 0; mt < 4; mt++) a[nxt][mt] = *(const short8v*)(arow[mt] + kk + 32);
            #pragma unroll
            for (int nt = 0; nt < 4; nt++) b[nxt][nt] = *(const short8v*)(brow[nt] + kk + 32);
        }
        #pragma unroll
        for (int mt = 0; mt < 4; mt++)
            #pragma unroll
            for (int nt = 0; nt < 4; nt++)
                acc[mt][nt] = __builtin_amdgcn_mfma_f32_16x16x32_bf16(
                    a[cur][mt], b[cur][nt], acc[mt][nt], 0, 0, 0);
    }

    #pragma unroll
    for (int mt = 0; mt < 4; mt++) {
        int rbase = r0 + mt * 16 + quad * 4;             // 4 consecutive rows
        int c = rbase >> 10, rl = rbase & 1023;
        #pragma unroll
        for (int nt = 0; nt < 4; nt++) {
            int e = n0 + nt * 16 + l16;
            unsigned short h[4];
            #pragma unroll
            for (int i = 0; i < 4; i++) h[i] = f2bf(acc[mt][nt][i]);
            if (mat == 0) {
                #pragma unroll
                for (int i = 0; i < 4; i++) qb[(rbase + i) * 512 + e] = h[i];
            } else if (mat == 1) {
                #pragma unroll
                for (int i = 0; i < 4; i++) kb[(rbase + i) * 512 + e] = h[i];
                us4 p; p[0] = h[0]; p[1] = h[1]; p[2] = h[2]; p[3] = h[3];
                *(us4*)(kt + (c * 512 + e) * 1024 + rl) = p;
            } else {
                us4 p; p[0] = h[0]; p[1] = h[1]; p[2] = h[2]; p[3] = h[3];
                *(us4*)(vt + (c * 512 + e) * 1024 + rl) = p;
            }
        }
    }
}

// ---------------------------------------------------------------- K2: per-chunk G = sum_r v (x) k
__global__ __launch_bounds__(256) void state_kernel(
    const unsigned short* __restrict__ kt, const unsigned short* __restrict__ vt,
    float* __restrict__ G) {
    const int c = blockIdx.y;
    const int dTile = blockIdx.x >> 2, eTile = blockIdx.x & 3;
    const int tid = threadIdx.x, wid = tid >> 6, lane = tid & 63;
    const int quad = lane >> 4, l16 = lane & 15;
    const int d0 = dTile * 128 + (wid >> 1) * 64;
    const int e0 = eTile * 128 + (wid & 1) * 64;

    f32x4 acc[4][4];
    #pragma unroll
    for (int a = 0; a < 4; a++)
        #pragma unroll
        for (int b = 0; b < 4; b++) acc[a][b] = (f32x4)0.f;

    const unsigned short* ar[4];
    const unsigned short* br[4];
    #pragma unroll
    for (int mt = 0; mt < 4; mt++) ar[mt] = vt + (c * 512 + d0 + mt * 16 + l16) * 1024 + quad * 8;
    #pragma unroll
    for (int nt = 0; nt < 4; nt++) br[nt] = kt + (c * 512 + e0 + nt * 16 + l16) * 1024 + quad * 8;

    short8v a[2][4], b[2][4];
    #pragma unroll
    for (int mt = 0; mt < 4; mt++) a[0][mt] = *(const short8v*)(ar[mt]);
    #pragma unroll
    for (int nt = 0; nt < 4; nt++) b[0][nt] = *(const short8v*)(br[nt]);

    #pragma unroll 2
    for (int rl = 0; rl < 1024; rl += 32) {
        const int cur = (rl >> 5) & 1, nxt = cur ^ 1;
        if (rl < 992) {
            #pragma unroll
            for (int mt = 0; mt < 4; mt++) a[nxt][mt] = *(const short8v*)(ar[mt] + rl + 32);
            #pragma unroll
            for (int nt = 0; nt < 4; nt++) b[nxt][nt] = *(const short8v*)(br[nt] + rl + 32);
        }
        #pragma unroll
        for (int mt = 0; mt < 4; mt++)
            #pragma unroll
            for (int nt = 0; nt < 4; nt++)
                acc[mt][nt] = __builtin_amdgcn_mfma_f32_16x16x32_bf16(
                    a[cur][mt], b[cur][nt], acc[mt][nt], 0, 0, 0);
    }

    float* g = G + (size_t)c * 262144;
    #pragma unroll
    for (int mt = 0; mt < 4; mt++)
        #pragma unroll
        for (int nt = 0; nt < 4; nt++)
            #pragma unroll
            for (int i = 0; i < 4; i++)
                g[(d0 + mt * 16 + quad * 4 + i) * 512 + (e0 + nt * 16 + l16)] = acc[mt][nt][i];
}

// ---------------------------------------------------------------- K3: exclusive prefix over chunks
__global__ __launch_bounds__(256) void scan_kernel(const float* __restrict__ G,
                                                   const float* __restrict__ m0,
                                                   unsigned short* __restrict__ Sp) {
    int idx = blockIdx.x * 256 + threadIdx.x;   // (d,e) flat, 262144 total
    float s = m0[idx];
    for (int c = 0; c < 64; c++) {
        Sp[c * 262144 + idx] = f2bf(s);
        s += LR_ * G[c * 262144 + idx];
    }
}

// ---------------------------------------------------------------- K4: out = Q@Sp^T + intra
// 1024 blocks = 64 chunks x 16 tile-pairs {p, 31-p} (33 j-tiles each: balanced).
// Per round: 4 waves compute 4 full 32x32 score tiles (4 indep chains each),
// one barrier, PV over the 128-deep score panel. Score panel double-buffered.
__global__ __launch_bounds__(256) void out_kernel(
    const unsigned short* __restrict__ qb, const unsigned short* __restrict__ kb,
    const unsigned short* __restrict__ vt, const unsigned short* __restrict__ Sp,
    float* __restrict__ out) {
    __shared__ unsigned short Qs[32][520];      // +8 pad: 4-bank row rotation
    __shared__ unsigned short Ss[2][32][136];   // double-buffered 32x128 panel

    // XCD swizzle: chunk in low 3 bits so a chunk's working set stays on one XCD.
    const int bx = blockIdx.x;
    const int c  = (bx >> 7) * 8 + (bx & 7);     // 0..63
    const int p  = (bx >> 3) & 15;               // pair index 0..15
    const int tid = threadIdx.x, wid = tid >> 6, lane = tid & 63;
    const int quad = lane >> 4, l16 = lane & 15;

    // inter B-pointers (Sp[c], identical for both halves)
    const unsigned short* spc = Sp + (size_t)c * 262144;
    const unsigned short* brow[8];
    #pragma unroll
    for (int nt = 0; nt < 8; nt++)
        brow[nt] = spc + (wid * 128 + nt * 16 + l16) * 512 + quad * 8;

    #pragma unroll
    for (int half = 0; half < 2; ++half) {
        const int it = half ? (31 - p) : p;      // row tile 0..31
        __syncthreads();                         // Qs reuse guard
        { // stage Q tile [32][512] to LDS
            int row = tid >> 3, seg = tid & 7;
            const unsigned short* src = qb + (c * 1024 + it * 32 + row) * 512 + seg * 64;
            #pragma unroll
            for (int j = 0; j < 8; j++)
                *(short8v*)&Qs[row][seg * 64 + j * 8] = *(const short8v*)(src + j * 8);
        }
        __syncthreads();

        f32x4 acc[2][8];
        #pragma unroll
        for (int a = 0; a < 2; a++)
            #pragma unroll
            for (int b = 0; b < 8; b++) acc[a][b] = (f32x4)0.f;

        // ---- inter: acc += Q @ Sp[c]^T
        for (int kk = 0; kk < 512; kk += 32) {
            short8v a0 = *(const short8v*)&Qs[l16][kk + quad * 8];
            short8v a1 = *(const short8v*)&Qs[16 + l16][kk + quad * 8];
            #pragma unroll
            for (int nt = 0; nt < 8; nt++) {
                short8v b = *(const short8v*)(brow[nt] + kk);
                acc[0][nt] = __builtin_amdgcn_mfma_f32_16x16x32_bf16(a0, b, acc[0][nt], 0, 0, 0);
                acc[1][nt] = __builtin_amdgcn_mfma_f32_16x16x32_bf16(a1, b, acc[1][nt], 0, 0, 0);
            }
        }

        // ---- intra: rounds of 4 j-tiles, one per wave
        const int rounds = (it + 4) >> 2;
        for (int r = 0; r < rounds; ++r) {
            const int j0 = r * 4;
            const int j  = j0 + wid;             // this wave's j-tile
            const bool active = (j <= it);
            const int buf = r & 1;
            if (active) {
                f32x4 sc[2][2];
                #pragma unroll
                for (int a = 0; a < 2; a++)
                    #pragma unroll
                    for (int b = 0; b < 2; b++) sc[a][b] = (f32x4)0.f;
                const unsigned short* k0 =
                    kb + (c * 1024 + j * 32 + l16) * 512 + quad * 8;
                const unsigned short* k1 = k0 + 16 * 512;
                for (int kk = 0; kk < 512; kk += 32) {
                    short8v a0 = *(const short8v*)&Qs[l16][kk + quad * 8];
                    short8v a1 = *(const short8v*)&Qs[16 + l16][kk + quad * 8];
                    short8v b0 = *(const short8v*)(k0 + kk);
                    short8v b1 = *(const short8v*)(k1 + kk);
                    sc[0][0] = __builtin_amdgcn_mfma_f32_16x16x32_bf16(a0, b0, sc[0][0], 0, 0, 0);
                    sc[0][1] = __builtin_amdgcn_mfma_f32_16x16x32_bf16(a0, b1, sc[0][1], 0, 0, 0);
                    sc[1][0] = __builtin_amdgcn_mfma_f32_16x16x32_bf16(a1, b0, sc[1][0], 0, 0, 0);
                    sc[1][1] = __builtin_amdgcn_mfma_f32_16x16x32_bf16(a1, b1, sc[1][1], 0, 0, 0);
                }
                if (j == it) sc[0][1] = (f32x4)0.f;   // diagonal: zero (t-sub 0, s-sub 1)
                #pragma unroll
                for (int mi = 0; mi < 2; mi++)
                    #pragma unroll
                    for (int ni = 0; ni < 2; ni++)
                        #pragma unroll
                        for (int i = 0; i < 4; i++)
                            Ss[buf][mi * 16 + quad * 4 + i][wid * 32 + ni * 16 + l16] =
                                f2bf(sc[mi][ni][i] * LR_);
            }
            __syncthreads();
            const int kmax = (it + 1 - j0 < 4) ? (it + 1 - j0) : 4;
            for (int kt4 = 0; kt4 < kmax; kt4++) {
                short8v as0 = *(const short8v*)&Ss[buf][l16][kt4 * 32 + quad * 8];
                short8v as1 = *(const short8v*)&Ss[buf][16 + l16][kt4 * 32 + quad * 8];
                const int rl = (j0 + kt4) * 32 + quad * 8;
                #pragma unroll
                for (int nt = 0; nt < 8; nt++) {
                    short8v bv = *(const short8v*)(
                        vt + (c * 512 + wid * 128 + nt * 16 + l16) * 1024 + rl);
                    acc[0][nt] = __builtin_amdgcn_mfma_f32_16x16x32_bf16(as0, bv, acc[0][nt], 0, 0, 0);
                    acc[1][nt] = __builtin_amdgcn_mfma_f32_16x16x32_bf16(as1, bv, acc[1][nt], 0, 0, 0);
                }
            }
            // no trailing barrier: next round writes the other buffer; the
            // per-round barrier above orders write(buf^1) after all reads(buf^1).
        }

        // ---- epilogue: out[b][t][d] fp32
        #pragma unroll
        for (int mt = 0; mt < 2; mt++)
            #pragma unroll
            for (int i = 0; i < 4; i++) {
                int r = c * 1024 + it * 32 + mt * 16 + quad * 4 + i;
                float* orow = out + (size_t)(r & 15) * (4096 * 512) + (size_t)(r >> 4) * 512;
                #pragma unroll
                for (int nt = 0; nt < 8; nt++)
                    orow[wid * 128 + nt * 16 + l16] = acc[mt][nt][i];
            }
    }
}

// ---------------------------------------------------------------- launch
extern "C" void kernel_launch(void* const* d_in, const int* in_sizes, int n_in,
                              void* d_out, int out_size, void* d_ws, size_t ws_size,
                              hipStream_t stream) {
    (void)in_sizes; (void)n_in; (void)out_size; (void)ws_size;
    const float* x  = (const float*)d_in[0];
    const float* Wq = (const float*)d_in[1];
    const float* Wk = (const float*)d_in[2];
    const float* Wv = (const float*)d_in[3];
    const float* m0 = (const float*)d_in[4];

    char* w = (char*)d_ws;
    unsigned short* xb = (unsigned short*)(w + 0);            //  64 MB
    unsigned short* wb = (unsigned short*)(w + 67108864);     // 1.5 MB
    unsigned short* qb = (unsigned short*)(w + 68681728);     //  64 MB  [r][e]
    unsigned short* kb = (unsigned short*)(w + 135790592);    //  64 MB  [r][e]
    unsigned short* kt = (unsigned short*)(w + 202899456);    //  64 MB  [c][e][rl]
    unsigned short* vt = (unsigned short*)(w + 270008320);    //  64 MB  [c][d][rl]
    float*          G  = (float*)(w + 337117184);             //  64 MB  [c][d][e]
    unsigned short* Sp = (unsigned short*)(w + 404226048);    //  32 MB  [c][d][e]

    cvt_kernel<<<16384, 256, 0, stream>>>(x, xb, 33554432);
    cvt_kernel<<<128, 256, 0, stream>>>(Wq, wb, 262144);
    cvt_kernel<<<128, 256, 0, stream>>>(Wk, wb + 262144, 262144);
    cvt_kernel<<<128, 256, 0, stream>>>(Wv, wb + 524288, 262144);

    proj_kernel<<<dim3(4, 512, 3), 256, 0, stream>>>(xb, wb, qb, kb, kt, vt);
    state_kernel<<<dim3(16, 64), 256, 0, stream>>>(kt, vt, G);
    scan_kernel<<<1024, 256, 0, stream>>>(G, m0, Sp);
    out_kernel<<<1024, 256, 0, stream>>>(qb, kb, vt, Sp, (float*)d_out);
}